// Round 12
// baseline (7791.140 us; speedup 1.0000x reference)
//
#include <hip/hip_runtime.h>
#include <cmath>

#define L_ 512
#define B_ 128
#define D_ 1024
#define H_ 1024

typedef __attribute__((ext_vector_type(8))) short bf16x8;
typedef __attribute__((ext_vector_type(4))) float f32x4;

static __device__ __forceinline__ unsigned short f32_bf16_rn(float f) {
  unsigned u = __float_as_uint(f);
  u += 0x7FFFu + ((u >> 16) & 1u);
  return (unsigned short)(u >> 16);
}
static __device__ __forceinline__ float bf16_f32(unsigned short h) {
  return __uint_as_float(((unsigned)h) << 16);
}

static __device__ __forceinline__ void pack8(const float4& u, const float4& v,
                                             bf16x8& hi, bf16x8& lo) {
  float f[8] = {u.x, u.y, u.z, u.w, v.x, v.y, v.z, v.w};
#pragma unroll
  for (int i = 0; i < 8; ++i) {
    const unsigned short h = f32_bf16_rn(f[i]);
    hi[i] = (short)h;
    lo[i] = (short)f32_bf16_rn(f[i] - bf16_f32(h));
  }
}

// ---------------------------------------------------------------------------
// Kernel A: xi = x @ Wi^T + bi, split-bf16 3-MFMA. (unchanged — R7-proven)
// ---------------------------------------------------------------------------
__global__ __launch_bounds__(256) void xi_gemm_mfma(
    const float* __restrict__ x, const float* __restrict__ Wi,
    const float* __restrict__ bi, float* __restrict__ out) {
  __shared__ unsigned short Ahi[128 * 32], Alo[128 * 32];
  __shared__ unsigned short Bhi[128 * 32], Blo[128 * 32];
  const int tid = threadIdx.x;
  const int bm = blockIdx.x, bn = blockIdx.y;
  const int lane = tid & 63, wv = tid >> 6;
  const int wm = wv >> 1, wn = wv & 1;

  const float* Ag = x + (size_t)bm * 128 * D_;
  const float* Bg = Wi + (size_t)bn * 128 * D_;

  f32x4 acc[4][4];
#pragma unroll
  for (int mi = 0; mi < 4; ++mi)
#pragma unroll
    for (int nj = 0; nj < 4; ++nj) acc[mi][nj] = (f32x4){0.f, 0.f, 0.f, 0.f};

  const int r = tid >> 1;
  const int h2 = tid & 1;
  const int sw = r & 3;
  const int s0 = (h2 * 2) ^ sw, s1 = (h2 * 2 + 1) ^ sw;
  const int fr = lane & 15, kg = lane >> 4;

  for (int k0 = 0; k0 < D_; k0 += 32) {
    __syncthreads();
    {
      const float* pa = &Ag[(size_t)r * D_ + k0 + h2 * 16];
      const float* pb = &Bg[(size_t)r * D_ + k0 + h2 * 16];
      const float4 a0 = *(const float4*)(pa + 0), a1 = *(const float4*)(pa + 4);
      const float4 a2 = *(const float4*)(pa + 8), a3 = *(const float4*)(pa + 12);
      const float4 b0 = *(const float4*)(pb + 0), b1 = *(const float4*)(pb + 4);
      const float4 b2 = *(const float4*)(pb + 8), b3 = *(const float4*)(pb + 12);
      bf16x8 h, l;
      pack8(a0, a1, h, l);
      *(bf16x8*)&Ahi[r * 32 + s0 * 8] = h;
      *(bf16x8*)&Alo[r * 32 + s0 * 8] = l;
      pack8(a2, a3, h, l);
      *(bf16x8*)&Ahi[r * 32 + s1 * 8] = h;
      *(bf16x8*)&Alo[r * 32 + s1 * 8] = l;
      pack8(b0, b1, h, l);
      *(bf16x8*)&Bhi[r * 32 + s0 * 8] = h;
      *(bf16x8*)&Blo[r * 32 + s0 * 8] = l;
      pack8(b2, b3, h, l);
      *(bf16x8*)&Bhi[r * 32 + s1 * 8] = h;
      *(bf16x8*)&Blo[r * 32 + s1 * 8] = l;
    }
    __syncthreads();

    bf16x8 Ah[4], Al[4], Bh[4], Bl[4];
#pragma unroll
    for (int mi = 0; mi < 4; ++mi) {
      const int row = wm * 64 + mi * 16 + fr;
      const int sl = kg ^ (row & 3);
      Ah[mi] = *(const bf16x8*)&Ahi[row * 32 + sl * 8];
      Al[mi] = *(const bf16x8*)&Alo[row * 32 + sl * 8];
    }
#pragma unroll
    for (int nj = 0; nj < 4; ++nj) {
      const int row = wn * 64 + nj * 16 + fr;
      const int sl = kg ^ (row & 3);
      Bh[nj] = *(const bf16x8*)&Bhi[row * 32 + sl * 8];
      Bl[nj] = *(const bf16x8*)&Blo[row * 32 + sl * 8];
    }
#pragma unroll
    for (int mi = 0; mi < 4; ++mi)
#pragma unroll
      for (int nj = 0; nj < 4; ++nj) {
        acc[mi][nj] = __builtin_amdgcn_mfma_f32_16x16x32_bf16(
            Ah[mi], Bh[nj], acc[mi][nj], 0, 0, 0);
        acc[mi][nj] = __builtin_amdgcn_mfma_f32_16x16x32_bf16(
            Ah[mi], Bl[nj], acc[mi][nj], 0, 0, 0);
        acc[mi][nj] = __builtin_amdgcn_mfma_f32_16x16x32_bf16(
            Al[mi], Bh[nj], acc[mi][nj], 0, 0, 0);
      }
  }

  const int fq = lane >> 4;
#pragma unroll
  for (int nj = 0; nj < 4; ++nj) {
    const int col = bn * 128 + wn * 64 + nj * 16 + fr;
    const float bias = bi[col];
#pragma unroll
    for (int mi = 0; mi < 4; ++mi)
#pragma unroll
      for (int reg = 0; reg < 4; ++reg) {
        const size_t row = (size_t)bm * 128 + wm * 64 + mi * 16 + fq * 4 + reg;
        out[row * H_ + col] = acc[mi][nj][reg] + bias;
      }
  }
}

// ---------------------------------------------------------------------------
// Kernel B v12: h_t = tanh(xi_t + h_{t-1} @ Wh^T + bh) — MFMA core,
// DATAFLOW SYNC (no global group barrier on the consumer side).
//
// Dependency analysis: wave wv consumes k in [wv*256, wv*256+256); producer
// of h[.][j'] is block c' = j'>>4, so k-tile kt needs exactly the flag pair
// {wv*16+2kt, +1} — one aligned 64-bit load. Per-wave per-kt poll, software-
// pipelined (pair kt+1 issued before kt's MFMAs -> latency hidden). Critical
// path = max of 2 relevant producers, not max of all 64 (straggler tail cut);
// post-poll __syncthreads deleted (waves fully decoupled on consume side).
// Self-pair (c'==own c) skipped: own data drained before own release barrier.
// Release path verbatim R2-lineage: vmcnt(0) -> __syncthreads -> tid0
// publishes flags[c]=t+1. Deadlock-free: deps strictly t-1 -> t, flags
// monotonic. h loads stay bypass (no fence anywhere, R11-proven).
// ---------------------------------------------------------------------------
__global__ __launch_bounds__(256, 2) void rnn_scan(
    const float* __restrict__ h0, const float* __restrict__ Wh,
    const float* __restrict__ bh, float* __restrict__ out,
    unsigned int* __restrict__ flags) {
  __shared__ unsigned short WhHi[16 * 1024];  // 32 KB
  __shared__ unsigned short WhLo[16 * 1024];  // 32 KB
  __shared__ float red[4 * 16 * 17];          // 4.25 KB, stride-17 pad
  const int tid = threadIdx.x;
  const int g = blockIdx.x & 7;
  const int c = blockIdx.x >> 3;
  const int j0 = c << 4;
  const int b0 = g << 4;

  // ---- Stage Wh rows j0..j0+15 as split-bf16, fragment-swizzled (once) ----
#pragma unroll
  for (int i = 0; i < 8; ++i) {
    const int sid = i * 256 + tid;
    const int jr = sid >> 7;
    const int s = sid & 127;
    const float* p = &Wh[(size_t)(j0 + jr) * H_ + s * 8];
    const float4 u = *(const float4*)(p);
    const float4 v4 = *(const float4*)(p + 4);
    bf16x8 hi, lo;
    pack8(u, v4, hi, lo);
    const int ps = s ^ (jr & 7);
    *(bf16x8*)&WhHi[jr * 1024 + ps * 8] = hi;
    *(bf16x8*)&WhLo[jr * 1024 + ps * 8] = lo;
  }

  const int lane = tid & 63;
  const int wv = tid >> 6;
  const int fr = lane & 15;
  const int kb = lane >> 4;
  const int frx7 = fr & 7;
  const int frt = fr * 1024;
  const int wvk = wv * 256;
  const int jq = lane >> 4;
  const int db = lane & 15;
  const int jf = tid & 15;
  const int bf = tid >> 4;
  const float bias = bh[j0 + jf];
  unsigned int* gflags = flags + (g << 6);
  const unsigned long long* fpair64 = (const unsigned long long*)gflags;
  __syncthreads();

  const unsigned long long* h64 =
      (const unsigned long long*)(h0 + (size_t)b0 * H_);
  const size_t hoff64 = (size_t)fr * (H_ / 2) + kb * 4;
  const size_t obase = (size_t)(b0 + bf) * H_ + (j0 + jf);
  float xi_cur = out[obase];  // xi[t=0] (line exclusively ours)
  for (int t = 0; t < L_; ++t) {
    f32x4 acc = (f32x4){0.f, 0.f, 0.f, 0.f};
    const unsigned tgt = (unsigned)t;
    // first pair poll value (t=0: tgt=0 -> trivially satisfied)
    unsigned long long fp = __hip_atomic_load(&fpair64[wv << 3],
                                              __ATOMIC_RELAXED,
                                              __HIP_MEMORY_SCOPE_AGENT);
#pragma unroll
    for (int kt = 0; kt < 8; ++kt) {
      const int p = (wv << 3) + kt;
      const int c0p = p << 1, c1p = c0p + 1;
      // ---- wait for the 2 producers of this k-tile (self-pair skipped) ----
      while (!(((unsigned)fp >= tgt) | (c0p == c)) ||
             !(((unsigned)(fp >> 32) >= tgt) | (c1p == c)))
        fp = __hip_atomic_load(&fpair64[p], __ATOMIC_RELAXED,
                               __HIP_MEMORY_SCOPE_AGENT);
      // ---- issue next pair's poll EARLY (latency hides under MFMA) ----
      unsigned long long fp_nxt = 0;
      if (kt < 7)
        fp_nxt = __hip_atomic_load(&fpair64[p + 1], __ATOMIC_RELAXED,
                                   __HIP_MEMORY_SCOPE_AGENT);
      // ---- h bypass loads + pack + MFMA (v11 body) ----
      const size_t k64 = hoff64 + (wvk >> 1) + kt * 16;
      const unsigned long long p0 = __hip_atomic_load(
          &h64[k64 + 0], __ATOMIC_RELAXED, __HIP_MEMORY_SCOPE_AGENT);
      const unsigned long long p1 = __hip_atomic_load(
          &h64[k64 + 1], __ATOMIC_RELAXED, __HIP_MEMORY_SCOPE_AGENT);
      const unsigned long long p2 = __hip_atomic_load(
          &h64[k64 + 2], __ATOMIC_RELAXED, __HIP_MEMORY_SCOPE_AGENT);
      const unsigned long long p3 = __hip_atomic_load(
          &h64[k64 + 3], __ATOMIC_RELAXED, __HIP_MEMORY_SCOPE_AGENT);
      const float4 u = make_float4(__uint_as_float((unsigned)p0),
                                   __uint_as_float((unsigned)(p0 >> 32)),
                                   __uint_as_float((unsigned)p1),
                                   __uint_as_float((unsigned)(p1 >> 32)));
      const float4 v4 = make_float4(__uint_as_float((unsigned)p2),
                                    __uint_as_float((unsigned)(p2 >> 32)),
                                    __uint_as_float((unsigned)p3),
                                    __uint_as_float((unsigned)(p3 >> 32)));
      bf16x8 Bh, Bl;
      pack8(u, v4, Bh, Bl);
      const int ps = (((wvk + kt * 32) >> 3) + kb) ^ frx7;
      const bf16x8 Ah = *(const bf16x8*)&WhHi[frt + ps * 8];
      const bf16x8 Al = *(const bf16x8*)&WhLo[frt + ps * 8];
      acc = __builtin_amdgcn_mfma_f32_16x16x32_bf16(Ah, Bh, acc, 0, 0, 0);
      acc = __builtin_amdgcn_mfma_f32_16x16x32_bf16(Ah, Bl, acc, 0, 0, 0);
      acc = __builtin_amdgcn_mfma_f32_16x16x32_bf16(Al, Bh, acc, 0, 0, 0);
      fp = fp_nxt;
    }
    const size_t oidx = (size_t)t * B_ * H_ + obase;
    // xi[t+1] prefetch (plain cached; line exclusively ours; register carry)
    const size_t oidx_n = oidx + (size_t)(t + 1 < L_ ? B_ * H_ : 0);
    const float xi_next = out[oidx_n];
    // K-partials -> LDS (D map: col=lane&15 -> b, row=(lane>>4)*4+reg -> j)
#pragma unroll
    for (int r4 = 0; r4 < 4; ++r4)
      red[(wv * 16 + jq * 4 + r4) * 17 + db] = acc[r4];
    __syncthreads();
    const float sum = red[(0 * 16 + jf) * 17 + bf] + red[(1 * 16 + jf) * 17 + bf] +
                      red[(2 * 16 + jf) * 17 + bf] + red[(3 * 16 + jf) * 17 + bf];
    const float v = tanhf(sum + xi_cur + bias);
    __hip_atomic_store(&out[oidx], v, __ATOMIC_RELAXED, __HIP_MEMORY_SCOPE_AGENT);

    if (t + 1 < L_) {
      // ---- release (R2-lineage, verbatim): drain, block done, publish ----
      asm volatile("s_waitcnt vmcnt(0)" ::: "memory");
      __syncthreads();
      if (tid == 0)
        __hip_atomic_store(&gflags[c], (unsigned)(t + 1), __ATOMIC_RELAXED,
                           __HIP_MEMORY_SCOPE_AGENT);
      // NO consumer-side barrier: next step's per-wave polls gate the reads.
    }
    xi_cur = xi_next;
    h64 = (const unsigned long long*)(out + (size_t)t * B_ * H_ +
                                      (size_t)b0 * H_);
  }
}

// ---------------------------------------------------------------------------
extern "C" void kernel_launch(void* const* d_in, const int* in_sizes, int n_in,
                              void* d_out, int out_size, void* d_ws, size_t ws_size,
                              hipStream_t stream) {
  const float* x    = (const float*)d_in[0];
  const float* h0   = (const float*)d_in[1];
  const float* Wi_w = (const float*)d_in[2];
  const float* Wi_b = (const float*)d_in[3];
  const float* Wh_w = (const float*)d_in[4];
  const float* Wh_b = (const float*)d_in[5];
  float* out = (float*)d_out;
  unsigned int* flags = (unsigned int*)d_ws;

  // Phase 1: xi -> d_out (split-bf16 MFMA)
  hipLaunchKernelGGL(xi_gemm_mfma, dim3(512, 8), dim3(256), 0, stream,
                     x, Wi_w, Wi_b, out);

  // Zero the barrier flags (graph replays reuse d_ws; flags must start 0)
  hipMemsetAsync(d_ws, 0, 4096, stream);

  // Phase 2: cooperative scan (MFMA core, dataflow sync)
  void* args[] = { (void*)&h0, (void*)&Wh_w, (void*)&Wh_b, (void*)&out, (void*)&flags };
  hipLaunchCooperativeKernel((void*)rnn_scan, dim3(512), dim3(256), args, 0, stream);
}

// Round 13
// 5273.257 us; speedup vs baseline: 1.4775x; 1.4775x over previous
//
#include <hip/hip_runtime.h>
#include <cmath>

#define L_ 512
#define B_ 128
#define D_ 1024
#define H_ 1024

typedef __attribute__((ext_vector_type(8))) short bf16x8;
typedef __attribute__((ext_vector_type(4))) float f32x4;

static __device__ __forceinline__ unsigned short f32_bf16_rn(float f) {
  unsigned u = __float_as_uint(f);
  u += 0x7FFFu + ((u >> 16) & 1u);
  return (unsigned short)(u >> 16);
}
static __device__ __forceinline__ float bf16_f32(unsigned short h) {
  return __uint_as_float(((unsigned)h) << 16);
}

static __device__ __forceinline__ void pack8(const float4& u, const float4& v,
                                             bf16x8& hi, bf16x8& lo) {
  float f[8] = {u.x, u.y, u.z, u.w, v.x, v.y, v.z, v.w};
#pragma unroll
  for (int i = 0; i < 8; ++i) {
    const unsigned short h = f32_bf16_rn(f[i]);
    hi[i] = (short)h;
    lo[i] = (short)f32_bf16_rn(f[i] - bf16_f32(h));
  }
}

// ---------------------------------------------------------------------------
// Kernel A: xi = x @ Wi^T + bi, split-bf16 3-MFMA. (unchanged — R7-proven)
// ---------------------------------------------------------------------------
__global__ __launch_bounds__(256) void xi_gemm_mfma(
    const float* __restrict__ x, const float* __restrict__ Wi,
    const float* __restrict__ bi, float* __restrict__ out) {
  __shared__ unsigned short Ahi[128 * 32], Alo[128 * 32];
  __shared__ unsigned short Bhi[128 * 32], Blo[128 * 32];
  const int tid = threadIdx.x;
  const int bm = blockIdx.x, bn = blockIdx.y;
  const int lane = tid & 63, wv = tid >> 6;
  const int wm = wv >> 1, wn = wv & 1;

  const float* Ag = x + (size_t)bm * 128 * D_;
  const float* Bg = Wi + (size_t)bn * 128 * D_;

  f32x4 acc[4][4];
#pragma unroll
  for (int mi = 0; mi < 4; ++mi)
#pragma unroll
    for (int nj = 0; nj < 4; ++nj) acc[mi][nj] = (f32x4){0.f, 0.f, 0.f, 0.f};

  const int r = tid >> 1;
  const int h2 = tid & 1;
  const int sw = r & 3;
  const int s0 = (h2 * 2) ^ sw, s1 = (h2 * 2 + 1) ^ sw;
  const int fr = lane & 15, kg = lane >> 4;

  for (int k0 = 0; k0 < D_; k0 += 32) {
    __syncthreads();
    {
      const float* pa = &Ag[(size_t)r * D_ + k0 + h2 * 16];
      const float* pb = &Bg[(size_t)r * D_ + k0 + h2 * 16];
      const float4 a0 = *(const float4*)(pa + 0), a1 = *(const float4*)(pa + 4);
      const float4 a2 = *(const float4*)(pa + 8), a3 = *(const float4*)(pa + 12);
      const float4 b0 = *(const float4*)(pb + 0), b1 = *(const float4*)(pb + 4);
      const float4 b2 = *(const float4*)(pb + 8), b3 = *(const float4*)(pb + 12);
      bf16x8 h, l;
      pack8(a0, a1, h, l);
      *(bf16x8*)&Ahi[r * 32 + s0 * 8] = h;
      *(bf16x8*)&Alo[r * 32 + s0 * 8] = l;
      pack8(a2, a3, h, l);
      *(bf16x8*)&Ahi[r * 32 + s1 * 8] = h;
      *(bf16x8*)&Alo[r * 32 + s1 * 8] = l;
      pack8(b0, b1, h, l);
      *(bf16x8*)&Bhi[r * 32 + s0 * 8] = h;
      *(bf16x8*)&Blo[r * 32 + s0 * 8] = l;
      pack8(b2, b3, h, l);
      *(bf16x8*)&Bhi[r * 32 + s1 * 8] = h;
      *(bf16x8*)&Blo[r * 32 + s1 * 8] = l;
    }
    __syncthreads();

    bf16x8 Ah[4], Al[4], Bh[4], Bl[4];
#pragma unroll
    for (int mi = 0; mi < 4; ++mi) {
      const int row = wm * 64 + mi * 16 + fr;
      const int sl = kg ^ (row & 3);
      Ah[mi] = *(const bf16x8*)&Ahi[row * 32 + sl * 8];
      Al[mi] = *(const bf16x8*)&Alo[row * 32 + sl * 8];
    }
#pragma unroll
    for (int nj = 0; nj < 4; ++nj) {
      const int row = wn * 64 + nj * 16 + fr;
      const int sl = kg ^ (row & 3);
      Bh[nj] = *(const bf16x8*)&Bhi[row * 32 + sl * 8];
      Bl[nj] = *(const bf16x8*)&Blo[row * 32 + sl * 8];
    }
#pragma unroll
    for (int mi = 0; mi < 4; ++mi)
#pragma unroll
      for (int nj = 0; nj < 4; ++nj) {
        acc[mi][nj] = __builtin_amdgcn_mfma_f32_16x16x32_bf16(
            Ah[mi], Bh[nj], acc[mi][nj], 0, 0, 0);
        acc[mi][nj] = __builtin_amdgcn_mfma_f32_16x16x32_bf16(
            Ah[mi], Bl[nj], acc[mi][nj], 0, 0, 0);
        acc[mi][nj] = __builtin_amdgcn_mfma_f32_16x16x32_bf16(
            Al[mi], Bh[nj], acc[mi][nj], 0, 0, 0);
      }
  }

  const int fq = lane >> 4;
#pragma unroll
  for (int nj = 0; nj < 4; ++nj) {
    const int col = bn * 128 + wn * 64 + nj * 16 + fr;
    const float bias = bi[col];
#pragma unroll
    for (int mi = 0; mi < 4; ++mi)
#pragma unroll
      for (int reg = 0; reg < 4; ++reg) {
        const size_t row = (size_t)bm * 128 + wm * 64 + mi * 16 + fq * 4 + reg;
        out[row * H_ + col] = acc[mi][nj][reg] + bias;
      }
  }
}

// ---------------------------------------------------------------------------
// Kernel B v13: h_t = tanh(xi_t + h_{t-1} @ Wh^T + bh)
//
// Sync skeleton & primitives VERBATIM v11 (R2-lineage: vmcnt -> syncthreads
// -> tid0 publish -> wave0 poll -> syncthreads; bypass h loads; no fences).
// [v12's per-k-tile dataflow polls regressed: N sequential MALL round-trips
//  beat by one overlapped group wait. Reverted.]
//
// Changed axis: TILING/GRID. 256 blocks (1/CU), 32 j-rows per block,
// 8 groups x 32 blocks (g=bid&7, c=bid>>3, j0=c*32).
//  * Wave (jh=wv>>1, kh=wv&1): output rows jh*16..+15, K-half kh (16 k-tiles
//    of 32). 2-way K-reduce via LDS red.
//  * Wh-hi: 32 rows in 64 KB LDS (proven-size), XOR-swizzled slots.
//    Wh-lo: 16x bf16x8 in REGISTERS per lane (64 VGPR; 1 blk/CU affords it).
//  * Why: (a) 1 block/CU kills co-resident same-group lockstep contention
//    (8 waves bursting on 4 SIMDs was ~2x compute-phase on every critical
//    path); (b) barrier tail max over 32 blocks, not 64; (c) bypass h
//    traffic halves (16 MB/step).
// ---------------------------------------------------------------------------
__global__ __launch_bounds__(256, 1) void rnn_scan(
    const float* __restrict__ h0, const float* __restrict__ Wh,
    const float* __restrict__ bh, float* __restrict__ out,
    unsigned int* __restrict__ flags) {
  __shared__ unsigned short WhHi[32 * 1024];  // 64 KB
  __shared__ float red[2 * 32 * 17];          // 4.25 KB (stride-17: no conflicts)
  const int tid = threadIdx.x;
  const int g = blockIdx.x & 7;
  const int c = blockIdx.x >> 3;
  const int j0 = c << 5;
  const int b0 = g << 4;

  // ---- Stage Wh-hi rows j0..j0+31 into LDS (once) ----
#pragma unroll
  for (int i = 0; i < 16; ++i) {
    const int sid = i * 256 + tid;      // 4096 slots of 8 floats
    const int jr = sid >> 7;            // 0..31
    const int s = sid & 127;            // k-slot
    const float* p = &Wh[(size_t)(j0 + jr) * H_ + s * 8];
    const float4 u = *(const float4*)(p);
    const float4 v4 = *(const float4*)(p + 4);
    bf16x8 hi, lo;
    pack8(u, v4, hi, lo);
    *(bf16x8*)&WhHi[jr * 1024 + (s ^ (jr & 7)) * 8] = hi;
  }

  const int lane = tid & 63;
  const int wv = tid >> 6;
  const int jh = wv >> 1;          // j-half (0,1)
  const int kh = wv & 1;           // K-half (0,1)
  const int fr = lane & 15;        // fragment row (j within half / batch)
  const int kb = lane >> 4;        // k-block within 32-k tile
  const int frx7 = fr & 7;
  const int jrt = (jh * 16 + fr) * 1024;  // LDS row base (shorts)

  // ---- Wh-lo -> registers: 16 k-tiles x 8 bf16 per lane ----
  bf16x8 wlo[16];
  {
    const float* wrow = Wh + (size_t)(j0 + jh * 16 + fr) * H_ + kh * 512;
#pragma unroll
    for (int kt = 0; kt < 16; ++kt) {
      const float* p = wrow + kt * 32 + kb * 8;
      const float4 u = *(const float4*)(p);
      const float4 v4 = *(const float4*)(p + 4);
      bf16x8 hi;
      pack8(u, v4, hi, wlo[kt]);
    }
  }

  // finisher mapping: 512 outputs over 256 threads (2 each)
  const int jf = tid & 31;
  const int bfh = tid >> 5;  // 0..7 -> batches bfh and bfh+8
  const float bias = bh[j0 + jf];
  unsigned int* gflags = flags + (g << 6);
  __syncthreads();

  const unsigned long long* h64 =
      (const unsigned long long*)(h0 + (size_t)b0 * H_);
  const size_t hoff64 = (size_t)fr * (H_ / 2) + kh * 256;  // 8B units
  const size_t obase0 = (size_t)(b0 + bfh) * H_ + (j0 + jf);
  const size_t obase1 = obase0 + (size_t)8 * H_;
  float xi0 = out[obase0];  // xi[t=0] — lines exclusively this block's
  float xi1 = out[obase1];
  for (int t = 0; t < L_; ++t) {
    f32x4 acc = (f32x4){0.f, 0.f, 0.f, 0.f};
#pragma unroll
    for (int kt = 0; kt < 16; ++kt) {
      const size_t k64 = hoff64 + kt * 16 + kb * 4;
      // Bypass loads: read the coherence point — no staleness, no fences.
      const unsigned long long p0 = __hip_atomic_load(
          &h64[k64 + 0], __ATOMIC_RELAXED, __HIP_MEMORY_SCOPE_AGENT);
      const unsigned long long p1 = __hip_atomic_load(
          &h64[k64 + 1], __ATOMIC_RELAXED, __HIP_MEMORY_SCOPE_AGENT);
      const unsigned long long p2 = __hip_atomic_load(
          &h64[k64 + 2], __ATOMIC_RELAXED, __HIP_MEMORY_SCOPE_AGENT);
      const unsigned long long p3 = __hip_atomic_load(
          &h64[k64 + 3], __ATOMIC_RELAXED, __HIP_MEMORY_SCOPE_AGENT);
      const float4 u = make_float4(__uint_as_float((unsigned)p0),
                                   __uint_as_float((unsigned)(p0 >> 32)),
                                   __uint_as_float((unsigned)p1),
                                   __uint_as_float((unsigned)(p1 >> 32)));
      const float4 v4 = make_float4(__uint_as_float((unsigned)p2),
                                    __uint_as_float((unsigned)(p2 >> 32)),
                                    __uint_as_float((unsigned)p3),
                                    __uint_as_float((unsigned)(p3 >> 32)));
      bf16x8 Bh, Bl;
      pack8(u, v4, Bh, Bl);
      const int ps = (kh * 64 + kt * 4 + kb) ^ frx7;
      const bf16x8 Ah = *(const bf16x8*)&WhHi[jrt + ps * 8];
      acc = __builtin_amdgcn_mfma_f32_16x16x32_bf16(Ah, Bh, acc, 0, 0, 0);
      acc = __builtin_amdgcn_mfma_f32_16x16x32_bf16(Ah, Bl, acc, 0, 0, 0);
      acc = __builtin_amdgcn_mfma_f32_16x16x32_bf16(wlo[kt], Bh, acc, 0, 0, 0);
    }
    const size_t tB = (size_t)t * B_ * H_;
    // xi[t+1] prefetch (plain cached; lines exclusively ours; reg carry)
    const size_t nB = tB + (size_t)(t + 1 < L_ ? B_ * H_ : 0);
    const float xin0 = out[nB + obase0];
    const float xin1 = out[nB + obase1];
    // K-partials -> LDS. D map: col=lane&15 -> b, row=(lane>>4)*4+reg -> j.
#pragma unroll
    for (int r4 = 0; r4 < 4; ++r4)
      red[(kh * 32 + jh * 16 + kb * 4 + r4) * 17 + fr] = acc[r4];
    __syncthreads();
    {
      const float s0 = red[(jf) * 17 + bfh] + red[(32 + jf) * 17 + bfh];
      const float s1 = red[(jf) * 17 + bfh + 8] + red[(32 + jf) * 17 + bfh + 8];
      const float v0 = tanhf(s0 + xi0 + bias);
      const float v1 = tanhf(s1 + xi1 + bias);
      __hip_atomic_store(&out[tB + obase0], v0, __ATOMIC_RELAXED,
                         __HIP_MEMORY_SCOPE_AGENT);
      __hip_atomic_store(&out[tB + obase1], v1, __ATOMIC_RELAXED,
                         __HIP_MEMORY_SCOPE_AGENT);
    }

    if (t + 1 < L_) {
      // ---- release: drain, block done, publish (R2-lineage, verbatim) ----
      asm volatile("s_waitcnt vmcnt(0)" ::: "memory");
      __syncthreads();
      if (tid == 0)
        __hip_atomic_store(&gflags[c], (unsigned)(t + 1), __ATOMIC_RELAXED,
                           __HIP_MEMORY_SCOPE_AGENT);
      // ---- wave 0: poll the 32 group flags (lanes duplicated x2) ----
      if (tid < 64) {
        const unsigned tgt = (unsigned)(t + 1);
        while (true) {
          const unsigned f = __hip_atomic_load(&gflags[tid & 31],
                                               __ATOMIC_RELAXED,
                                               __HIP_MEMORY_SCOPE_AGENT);
          if (__all((int)(f >= tgt))) break;
          __builtin_amdgcn_s_sleep(1);
        }
      }
      __syncthreads();
    }
    xi0 = xin0;
    xi1 = xin1;
    h64 = (const unsigned long long*)(out + tB + (size_t)b0 * H_);
  }
}

// ---------------------------------------------------------------------------
extern "C" void kernel_launch(void* const* d_in, const int* in_sizes, int n_in,
                              void* d_out, int out_size, void* d_ws, size_t ws_size,
                              hipStream_t stream) {
  const float* x    = (const float*)d_in[0];
  const float* h0   = (const float*)d_in[1];
  const float* Wi_w = (const float*)d_in[2];
  const float* Wi_b = (const float*)d_in[3];
  const float* Wh_w = (const float*)d_in[4];
  const float* Wh_b = (const float*)d_in[5];
  float* out = (float*)d_out;
  unsigned int* flags = (unsigned int*)d_ws;

  // Phase 1: xi -> d_out (split-bf16 MFMA)
  hipLaunchKernelGGL(xi_gemm_mfma, dim3(512, 8), dim3(256), 0, stream,
                     x, Wi_w, Wi_b, out);

  // Zero the barrier flags (graph replays reuse d_ws; flags must start 0)
  hipMemsetAsync(d_ws, 0, 4096, stream);

  // Phase 2: cooperative scan — 256 blocks (1/CU), 8 groups x 32 blocks
  void* args[] = { (void*)&h0, (void*)&Wh_w, (void*)&Wh_b, (void*)&out, (void*)&flags };
  hipLaunchCooperativeKernel((void*)rnn_scan, dim3(256), dim3(256), args, 0, stream);
}